// Round 1
// 163.071 us; speedup vs baseline: 1.0083x; 1.0083x over previous
//
#include <hip/hip_runtime.h>

// SpatialTransformer: 3D trilinear warp, zeros padding.
// src [B,C,D,H,W] f32 = [2,2,128,160,128]; flow [B,3,D,H,W]; out [B,C,D,H,W].
//
// R9: CHANNEL FUSION. flow is per-batch (shared by C=2 channels) but R8 put
// the channel in the grid -> flow fetched twice (63 MB extra HBM) and the
// whole coord/floor/clamp/weight chain (~40 VALU) computed twice per voxel.
//  - One block now produces BOTH channels: src tile staged channel-
//    interleaved [z][y][x][{c0,c1}] so one adjacent float2-pair LDS read
//    (ds_read2_b64) serves both channels at both x-corners.
//  - Coords/weights/bounds computed once per voxel-PAIR; flow read once.
//  - LDS doubles to 43.75 KB -> 512-thread blocks: 3 blocks/CU x 8 waves
//    = 24 waves/CU (R8 ceiling was 28, measured 21) ~ occupancy-neutral.
//  - Staging bytes per output voxel unchanged (5.47 floats/out).
//  - launch_bounds(512,6): VGPR cap ~85; body needs ~50-70 (R8 used 36),
//    loose enough to avoid the R5/R6 catastrophic-spill failure mode.
// Fallback (outside halo window): ~0.1% of voxels, exact global gather x2ch.

#define B_ 2
#define C_ 2
#define D_ 128
#define H_ 160
#define W_ 128
constexpr int S_ = D_ * H_ * W_;

#define ZT 4
#define YT 8
#define XT 32
#define RZ 3
#define RY 3
#define RX 4
#define CZ (ZT + 2 * RZ)   // 10
#define CY (YT + 2 * RY)   // 14
#define CX (XT + 2 * RX)   // 40
#define NTHREADS 512
#define NPAIR (ZT * YT * XT)           // 1024 voxel-pairs per block
#define PPT (NPAIR / NTHREADS)         // 2 pairs per thread
#define NCHUNK (CZ * CY * (CX / 2))    // 2800 16B chunks (x-pair x {c0,c1})

__device__ __forceinline__ float pair_val(const float* p, bool hi0, bool lo1,
                                          float wx0, float wx1) {
    const float v0 = hi0 ? p[1] : p[0];
    const float v1 = lo1 ? p[0] : p[1];
    return wx0 * v0 + wx1 * v1;
}

// Read both channels at x-corners (xp, xp+1) from the interleaved tile and
// x-blend. o = float index of [z][y][xp][c0]. Returns {ch0, ch1}.
__device__ __forceinline__ float2 lds_pair2(const float* t, int o,
                                            bool hi0, bool lo1,
                                            float wx0, float wx1) {
    const float2 a = *(const float2*)&t[o];       // {c0(xp),   c1(xp)}
    const float2 b = *(const float2*)&t[o + 2];   // {c0(xp+1), c1(xp+1)}
    const float v00 = hi0 ? b.x : a.x;            // ch0 value at x0
    const float v01 = lo1 ? a.x : b.x;            // ch0 value at x0+1
    const float v10 = hi0 ? b.y : a.y;            // ch1
    const float v11 = lo1 ? a.y : b.y;
    return make_float2(wx0 * v00 + wx1 * v01, wx0 * v10 + wx1 * v11);
}

__global__ __launch_bounds__(NTHREADS, 6) void warp3d_tile(
    const float* __restrict__ src,
    const float* __restrict__ flow,
    float* __restrict__ out)
{
    __shared__ float tile[CZ * CY * CX * 2];   // 11200 floats = 43.75 KB

    const int tid = threadIdx.x;
    const int xb = blockIdx.x * XT;
    const int yb = blockIdx.y * YT;
    const int bz = blockIdx.z;
    const int zb = (bz & 31) * ZT;         // 32 z-tiles
    const int b  = bz >> 5;                // batch

    const int zlo = max(0, zb - RZ), zhi = min(D_, zb + ZT + RZ);
    const int ylo = max(0, yb - RY), yhi = min(H_, yb + YT + RY);
    const int xlo = max(0, xb - RX), xhi = min(W_, xb + XT + RX);

    const float* fb = flow + (long long)b * 3 * S_;
    const float* s0 = src + (long long)b * C_ * S_;   // ch0; ch1 = s0 + S_
    float* o0       = out + (long long)b * C_ * S_;   // ch0; ch1 = o0 + S_

    // ---- stage src tile (+halo), both channels interleaved ----
    // chunk lin -> LDS bytes [lin*16, lin*16+16) = x-pair x {c0,c1}
#pragma unroll
    for (int j = 0; j < 6; ++j) {
        const int lin = j * NTHREADS + tid;
        if (lin < NCHUNK) {
            const int row = lin / 20;              // rz*CY+ry, 0..139
            const int c   = lin - row * 20;        // x-pair 0..19
            const int rz = row / CY, ry = row - rz * CY;
            const int gz = zb - RZ + rz;
            const int gy = yb - RY + ry;
            const int gx = xb - RX + c * 2;        // even
            if ((unsigned)gz < (unsigned)D_ && (unsigned)gy < (unsigned)H_ &&
                (unsigned)gx <= (unsigned)(W_ - 2)) {
                const int off = ((gz * H_ + gy) << 7) + gx;
                const float2 va = *(const float2*)(s0 + off);        // ch0
                const float2 vb = *(const float2*)(s0 + S_ + off);   // ch1
                *(float4*)&tile[lin * 4] = make_float4(va.x, vb.x, va.y, vb.y);
            }
        }
    }
    __syncthreads();

    // ---- compute: 1024 voxel-pairs, 2 per thread ----
#pragma unroll
    for (int it = 0; it < PPT; ++it) {
        const int vox = it * NTHREADS + tid;
        const int lx = vox & 31, ly = (vox >> 5) & 7, lz = vox >> 8;
        const int x = xb + lx, y = yb + ly, z = zb + lz;
        const int s = ((z * H_ + y) << 7) + x;

        const float fz = fb[s], fy = fb[S_ + s], fx = fb[2 * S_ + s];
        const float iz = (float)z + fz;
        const float iy = (float)y + fy;
        const float ix = (float)x + fx;

        const float zf = floorf(iz), yf = floorf(iy), xf = floorf(ix);
        const float tz = iz - zf, ty = iy - yf, tx = ix - xf;
        const int z0 = (int)zf, y0 = (int)yf, x0 = (int)xf;

        const int zc0 = min(max(z0, 0), D_ - 1), zc1 = min(max(z0 + 1, 0), D_ - 1);
        const int yc0 = min(max(y0, 0), H_ - 1), yc1 = min(max(y0 + 1, 0), H_ - 1);
        const int xp  = min(max(x0, 0), W_ - 2);

        const float wz0 = ((unsigned)z0       < (unsigned)D_) ? (1.f - tz) : 0.f;
        const float wz1 = ((unsigned)(z0 + 1) < (unsigned)D_) ? tz         : 0.f;
        const float wy0 = ((unsigned)y0       < (unsigned)H_) ? (1.f - ty) : 0.f;
        const float wy1 = ((unsigned)(y0 + 1) < (unsigned)H_) ? ty         : 0.f;
        const float wx0 = ((unsigned)x0       < (unsigned)W_) ? (1.f - tx) : 0.f;
        const float wx1 = ((unsigned)(x0 + 1) < (unsigned)W_) ? tx         : 0.f;
        const bool hi0 = x0 > xp;   // x0 == W-1
        const bool lo1 = x0 < xp;   // x0 == -1

        const bool fast = (zc0 >= zlo) & (zc1 < zhi) &
                          (yc0 >= ylo) & (yc1 < yhi) &
                          (xp >= xlo) & (xp + 1 < xhi);

        float acc0, acc1;
        if (fast) {
            const int izl0 = zc0 - (zb - RZ), izl1 = zc1 - (zb - RZ);
            const int iyl0 = yc0 - (yb - RY), iyl1 = yc1 - (yb - RY);
            const int ixl  = xp - (xb - RX);
            const int o00 = ((izl0 * CY + iyl0) * CX + ixl) * 2;
            const int o01 = ((izl0 * CY + iyl1) * CX + ixl) * 2;
            const int o10 = ((izl1 * CY + iyl0) * CX + ixl) * 2;
            const int o11 = ((izl1 * CY + iyl1) * CX + ixl) * 2;
            const float2 p00 = lds_pair2(tile, o00, hi0, lo1, wx0, wx1);
            const float2 p01 = lds_pair2(tile, o01, hi0, lo1, wx0, wx1);
            const float2 p10 = lds_pair2(tile, o10, hi0, lo1, wx0, wx1);
            const float2 p11 = lds_pair2(tile, o11, hi0, lo1, wx0, wx1);
            acc0 = wz0 * (wy0 * p00.x + wy1 * p01.x) + wz1 * (wy0 * p10.x + wy1 * p11.x);
            acc1 = wz0 * (wy0 * p00.y + wy1 * p01.y) + wz1 * (wy0 * p10.y + wy1 * p11.y);
        } else {
            const int l00 = ((zc0 * H_ + yc0) << 7) + xp;
            const int l01 = ((zc0 * H_ + yc1) << 7) + xp;
            const int l10 = ((zc1 * H_ + yc0) << 7) + xp;
            const int l11 = ((zc1 * H_ + yc1) << 7) + xp;
            const float q00 = pair_val(s0 + l00, hi0, lo1, wx0, wx1);
            const float q01 = pair_val(s0 + l01, hi0, lo1, wx0, wx1);
            const float q10 = pair_val(s0 + l10, hi0, lo1, wx0, wx1);
            const float q11 = pair_val(s0 + l11, hi0, lo1, wx0, wx1);
            const float r00 = pair_val(s0 + S_ + l00, hi0, lo1, wx0, wx1);
            const float r01 = pair_val(s0 + S_ + l01, hi0, lo1, wx0, wx1);
            const float r10 = pair_val(s0 + S_ + l10, hi0, lo1, wx0, wx1);
            const float r11 = pair_val(s0 + S_ + l11, hi0, lo1, wx0, wx1);
            acc0 = wz0 * (wy0 * q00 + wy1 * q01) + wz1 * (wy0 * q10 + wy1 * q11);
            acc1 = wz0 * (wy0 * r00 + wy1 * r01) + wz1 * (wy0 * r10 + wy1 * r11);
        }
        o0[s]      = acc0;
        o0[S_ + s] = acc1;
    }
}

extern "C" void kernel_launch(void* const* d_in, const int* in_sizes, int n_in,
                              void* d_out, int out_size, void* d_ws, size_t ws_size,
                              hipStream_t stream) {
    const float* src  = (const float*)d_in[0];
    const float* flow = (const float*)d_in[1];
    float* out = (float*)d_out;

    // grid: x 4, y 20, z = 32 z-tiles x B2 = 64  -> 5120 blocks (channel fused)
    dim3 grid(W_ / XT, H_ / YT, (D_ / ZT) * B_);
    warp3d_tile<<<grid, NTHREADS, 0, stream>>>(src, flow, out);
}